// Round 9
// baseline (262.023 us; speedup 1.0000x reference)
//
#include <hip/hip_runtime.h>
#include <hip/hip_bf16.h>

typedef __hip_bfloat16 bf16;
typedef _Float16 f16;
typedef __attribute__((ext_vector_type(8))) short bf16x8;
typedef __attribute__((ext_vector_type(8))) _Float16 f16x8;
typedef __attribute__((ext_vector_type(2))) _Float16 f16x2;
typedef __attribute__((ext_vector_type(4))) float f32x4;
typedef __attribute__((ext_vector_type(4))) unsigned int u32x4;
typedef __attribute__((ext_vector_type(2))) unsigned int u32x2;

#define B_ 4
#define N_ 4096
#define C_ 256
#define H_ 4
#define D_ 64
#define KLN 0.18033688011112042f   /* 0.125 * log2(e): folded into Q */

#if __has_builtin(__builtin_amdgcn_exp2f)
#define EXP2(x) __builtin_amdgcn_exp2f(x)
#else
#define EXP2(x) exp2f(x)
#endif
#if __has_builtin(__builtin_amdgcn_rcpf)
#define RCP(x) __builtin_amdgcn_rcpf(x)
#else
#define RCP(x) (1.0f / (x))
#endif

// direct global->LDS DMA, 16B per lane. LDS dest = wave-uniform base + lane*16.
__device__ inline void load_lds16(const void* g, void* l) {
#if __has_builtin(__builtin_amdgcn_global_load_lds)
    __builtin_amdgcn_global_load_lds(
        (const __attribute__((address_space(1))) unsigned int*)g,
        (__attribute__((address_space(3))) unsigned int*)l, 16, 0, 0);
#else
    int ln = __lane_id();
    ((u32x4*)l)[ln] = *((const u32x4*)g);   // fallback (not used on gfx950)
#endif
}

// two fp32 -> packed bf16 pair (round-half-up)
__device__ inline unsigned int pk2(float a, float b) {
    unsigned int ua = __builtin_bit_cast(unsigned int, a) + 0x8000u;
    unsigned int ub = __builtin_bit_cast(unsigned int, b) + 0x8000u;
    return (ua >> 16) | (ub & 0xffff0000u);
}
// two fp32 -> packed f16 pair (single v_cvt_pkrtz_f16_f32)
__device__ inline unsigned int pkh2(float a, float b) {
#if __has_builtin(__builtin_amdgcn_cvt_pkrtz)
    return __builtin_bit_cast(unsigned int, __builtin_amdgcn_cvt_pkrtz(a, b));
#else
    f16x2 h = { (f16)a, (f16)b };
    return __builtin_bit_cast(unsigned int, h);
#endif
}

// ---------------------------------------------------------------------------
// Prep: cast x, w_qkv, w_proj fp32 -> bf16 (memory-bound).
// ---------------------------------------------------------------------------
__global__ __launch_bounds__(256) void cast_bf16(const float* __restrict__ x,
                                                 const float* __restrict__ wq,
                                                 const float* __restrict__ wp,
                                                 bf16* __restrict__ xb,
                                                 bf16* __restrict__ wqb,
                                                 bf16* __restrict__ wpb)
{
    int bid = blockIdx.x;
    const float* s; bf16* d; int base;
    if (bid < 2048)      { s = x;  d = xb;  base = bid * 2048; }
    else if (bid < 2144) { s = wq; d = wqb; base = (bid - 2048) * 2048; }
    else                 { s = wp; d = wpb; base = (bid - 2144) * 2048; }
    int i = base + threadIdx.x * 8;
    f32x4 a = *reinterpret_cast<const f32x4*>(s + i);
    f32x4 b = *reinterpret_cast<const f32x4*>(s + i + 4);
    u32x4 o;
    o.x = pk2(a[0], a[1]); o.y = pk2(a[2], a[3]);
    o.z = pk2(b[0], b[1]); o.w = pk2(b[2], b[3]);
    *reinterpret_cast<u32x4*>(d + i) = o;
}

// ---------------------------------------------------------------------------
// QKV projection — round-3 version (best measured non-attn config).
// ---------------------------------------------------------------------------
__global__ __launch_bounds__(256, 2) void qkv_fast(const bf16* __restrict__ x,
                                                   const bf16* __restrict__ w,
                                                   bf16* __restrict__ qw,
                                                   bf16* __restrict__ kw,
                                                   f16* __restrict__ vtw)
{
    __shared__ short w_s[64][264];
    const int tid  = threadIdx.x;
    const int lane = tid & 63;
    const int wav  = tid >> 6;
    const int quad = lane >> 4;
    const int l16  = lane & 15;
    const int bid = (blockIdx.x & 7) * 192 + (blockIdx.x >> 3);   // 1536 = 8*192
    const int mt = bid / 12, nb = bid % 12;
    const int m0 = mt * 128, n0 = nb * 64;

    {
        const int row = tid >> 2, cb = (tid & 3) * 64;
        const bf16* src = w + (size_t)(n0 + row) * C_ + cb;
#pragma unroll
        for (int i = 0; i < 8; ++i)
            *reinterpret_cast<bf16x8*>(&w_s[row][cb + i * 8]) =
                *reinterpret_cast<const bf16x8*>(src + i * 8);
    }
    __syncthreads();

#pragma unroll
    for (int half = 0; half < 2; ++half) {
        const int mh = m0 + half * 64;
        f32x4 acc[4] = {{0,0,0,0},{0,0,0,0},{0,0,0,0},{0,0,0,0}};
        const bf16* xrow = x + (size_t)(mh + wav * 16 + l16) * C_ + quad * 8;
        if (nb < 8) {        // Q/K: transposed accumulator (swapped operands)
#pragma unroll
            for (int k0 = 0; k0 < C_; k0 += 32) {
                bf16x8 a = *reinterpret_cast<const bf16x8*>(xrow + k0);
#pragma unroll
                for (int nt = 0; nt < 4; ++nt) {
                    bf16x8 b = *reinterpret_cast<const bf16x8*>(&w_s[nt * 16 + l16][k0 + quad * 8]);
                    acc[nt] = __builtin_amdgcn_mfma_f32_16x16x32_bf16(b, a, acc[nt], 0, 0, 0);
                }
            }
        } else {             // V: normal orientation (store wants n-contiguous)
#pragma unroll
            for (int k0 = 0; k0 < C_; k0 += 32) {
                bf16x8 a = *reinterpret_cast<const bf16x8*>(xrow + k0);
#pragma unroll
                for (int nt = 0; nt < 4; ++nt) {
                    bf16x8 b = *reinterpret_cast<const bf16x8*>(&w_s[nt * 16 + l16][k0 + quad * 8]);
                    acc[nt] = __builtin_amdgcn_mfma_f32_16x16x32_bf16(a, b, acc[nt], 0, 0, 0);
                }
            }
        }

        const int bb = mh >> 12;
        const int nbase = (mh + wav * 16) & (N_ - 1);
        if (nb < 4) {                            // Q (scaled): row n = nbase+l16
            bf16* dst = qw + (((size_t)bb * H_ + nb) * N_ + nbase + l16) * D_;
#pragma unroll
            for (int nt = 0; nt < 4; ++nt) {
                u32x2 wv = { pk2(acc[nt][0] * KLN, acc[nt][1] * KLN),
                             pk2(acc[nt][2] * KLN, acc[nt][3] * KLN) };
                *reinterpret_cast<u32x2*>(dst + nt * 16 + quad * 4) = wv;
            }
        } else if (nb < 8) {                     // K
            bf16* dst = kw + (((size_t)bb * H_ + (nb - 4)) * N_ + nbase + l16) * D_;
#pragma unroll
            for (int nt = 0; nt < 4; ++nt) {
                u32x2 wv = { pk2(acc[nt][0], acc[nt][1]),
                             pk2(acc[nt][2], acc[nt][3]) };
                *reinterpret_cast<u32x2*>(dst + nt * 16 + quad * 4) = wv;
            }
        } else {                                 // V transposed, f16
            const int h = nb - 8;
#pragma unroll
            for (int nt = 0; nt < 4; ++nt) {
                int d = nt * 16 + l16;
                u32x2 wv;
                wv.x = pkh2(acc[nt][0], acc[nt][1]);
                wv.y = pkh2(acc[nt][2], acc[nt][3]);
                *reinterpret_cast<u32x2*>(
                    vtw + (((size_t)bb * H_ + h) * D_ + d) * N_ + nbase + quad * 4) = wv;
            }
        }
    }
}

// ---------------------------------------------------------------------------
// Flash attention v12 = r1/r7 structure + CROSS-TILE PV pipelining.
// r7 evidence: MfmaUtil 46 + VALUBusy 47, sum ~93 -> the per-wave chain
// QK(t)->exp(t)->PV(t) serializes the matrix and VALU pipes (all waves
// phase-locked by the tile barrier). v12 breaks the chain: PV consumes the
// PREVIOUS tile's P (held in registers), issued right after QK(t)'s MFMAs
// and BEFORE exp(t). The PV block then has no dependency on this tile's
// results -> the wave queues ~36 MFMAs back-to-back and exp(t) runs on the
// VALU while the matrix backlog drains. V gets a third LDS buffer (V(t-1)
// must outlive staging of V(t+1)): K 2x16KB + V 3x16KB = 80KB, still
// exactly 2 blocks/CU. The tile loop is unrolled x6 (lcm of K parity and
// V mod-3) so all buffer indices are compile-time constants. Accumulation
// order into oacc/lacc is preserved (tiles applied 0..31) -> bit-identical.
// ---------------------------------------------------------------------------
__global__ __launch_bounds__(512, 4) void attn(const bf16* __restrict__ q,
                                               const bf16* __restrict__ k,
                                               const f16* __restrict__ vt,
                                               bf16* __restrict__ o)
{
    __shared__ __align__(16) char smem[81920];
    short* k_s = reinterpret_cast<short*>(smem);            // [2][jh][4096]
    f16*   v_s = reinterpret_cast<f16*>(smem + 32768);      // [3][jh][4096]

    const int tid  = threadIdx.x;
    const int lane = tid & 63;
    const int wav  = tid >> 6;       // 0..7
    const int quad = lane >> 4;
    const int l16  = lane & 15;
    const int l8   = lane & 7;
    const int sub  = wav & 3;        // 32-row q-slice within the 128-row tile
    const int jh   = wav >> 2;       // j-half

    const int wg = (blockIdx.x & 7) * 64 + (blockIdx.x >> 3);  // XCD swizzle
    const int bh = wg >> 5;
    const int qt = wg & 31;
    const int bb = bh >> 2, h = bh & 3;

    const bf16* qp = q  + (size_t)bh * N_ * D_;
    const bf16* kp = k  + (size_t)bh * N_ * D_;
    const f16*  vp = vt + (size_t)bh * D_ * N_;

    const int qbase = qt * 128 + sub * 32;
    bf16x8 qb[2][2];
#pragma unroll
    for (int qg = 0; qg < 2; ++qg)
#pragma unroll
        for (int ks = 0; ks < 2; ++ks)
            qb[qg][ks] = *reinterpret_cast<const bf16x8*>(
                qp + (size_t)(qbase + qg * 16 + l16) * D_ + ks * 32 + quad * 8);

    // staging geometry: lane -> (row ri, stored slot ci); logical chunk = ci^ri
    const int ri = lane >> 3;
    const int ci = lane & 7;
    const int gc = ci ^ ri;
    int koff[2], voff[2], lds_r[2];
#pragma unroll
    for (int g = 0; g < 2; ++g) {
        const int rb  = sub * 16 + g * 8;
        const int rho = rb + ri;
        const int pr  = (rho & 32) | ((rho & 12) << 1) | ((rho & 16) >> 2) | (rho & 3);
        koff[g]  = pr * D_ + gc * 8;          // K: permuted row, swizzled chunk
        voff[g]  = rho * N_ + gc * 8;         // V: linear d-row, swizzled chunk
        lds_r[g] = rb * 64;
    }

    f32x4 oacc[2][4];
    f32x4 lacc[2];
#pragma unroll
    for (int qg = 0; qg < 2; ++qg) {
        lacc[qg] = (f32x4){0, 0, 0, 0};
#pragma unroll
        for (int dt = 0; dt < 4; ++dt) oacc[qg][dt] = (f32x4){0, 0, 0, 0};
    }
    const f16x8 onesA = {1.f16, 1.f16, 1.f16, 1.f16, 1.f16, 1.f16, 1.f16, 1.f16};

    auto stageKV = [&](int kbuf, int vslot, int t) {
        const int j0 = jh * 2048 + t * 64;
        short* kd = k_s + (size_t)(kbuf * 2 + jh) * 4096;
        f16*   vd = v_s + (size_t)(vslot * 2 + jh) * 4096;
#pragma unroll
        for (int g = 0; g < 2; ++g) {
            load_lds16(kp + (size_t)j0 * D_ + koff[g], kd + lds_r[g]);
            load_lds16(vp + j0 + voff[g],              vd + lds_r[g]);
        }
    };

    f32x4 s[2][4];            // this tile's S^T (QK output, pre-exp)
    f16x8 pbE[2][2], pbO[2][2];   // P fragments: even / odd tiles

    // QK(t): S^T = K.Q^T from K buffer kbuf into s[][]
    auto qk = [&](int kbuf) {
        const short* kt = k_s + (size_t)(kbuf * 2 + jh) * 4096;
        bf16x8 ka[4][2];
#pragma unroll
        for (int nt = 0; nt < 4; ++nt) {
            const int rb = (nt * 16 + l16) * 64;
            ka[nt][0] = *reinterpret_cast<const bf16x8*>(kt + rb + ((quad    ) ^ l8) * 8);
            ka[nt][1] = *reinterpret_cast<const bf16x8*>(kt + rb + ((4 + quad) ^ l8) * 8);
        }
#pragma unroll
        for (int qg = 0; qg < 2; ++qg)
#pragma unroll
            for (int nt = 0; nt < 4; ++nt) {
                s[qg][nt] = __builtin_amdgcn_mfma_f32_16x16x32_bf16(
                    ka[nt][0], qb[qg][0], (f32x4){0.f, 0.f, 0.f, 0.f}, 0, 0, 0);
                s[qg][nt] = __builtin_amdgcn_mfma_f32_16x16x32_bf16(
                    ka[nt][1], qb[qg][1], s[qg][nt], 0, 0, 0);
            }
    };

    // PV(t-1) + l(t-1): consumes pb from the PREVIOUS tile (no deps on s)
    auto pv = [&](int vslot, f16x8 (*pb)[2]) {
        const f16* vtl = v_s + (size_t)(vslot * 2 + jh) * 4096;
#pragma unroll
        for (int qg = 0; qg < 2; ++qg)
#pragma unroll
            for (int ks = 0; ks < 2; ++ks)
                lacc[qg] = __builtin_amdgcn_mfma_f32_16x16x32_f16(onesA, pb[qg][ks], lacc[qg], 0, 0, 0);
#pragma unroll
        for (int ks = 0; ks < 2; ++ks)
#pragma unroll
            for (int dt = 0; dt < 4; ++dt) {
                f16x8 va = *reinterpret_cast<const f16x8*>(
                    vtl + (dt * 16 + l16) * 64 + (((ks << 2) + quad) ^ l8) * 8);
                oacc[0][dt] = __builtin_amdgcn_mfma_f32_16x16x32_f16(va, pb[0][ks], oacc[0][dt], 0, 0, 0);
                oacc[1][dt] = __builtin_amdgcn_mfma_f32_16x16x32_f16(va, pb[1][ks], oacc[1][dt], 0, 0, 0);
            }
    };

    // exp(t): p = exp2(s) -> f16 fragments (VALU; overlaps PV's MFMA drain)
    auto expp = [&](f16x8 (*pb)[2]) {
#pragma unroll
        for (int qg = 0; qg < 2; ++qg)
#pragma unroll
            for (int ks = 0; ks < 2; ++ks) {
                const f32x4 sa = s[qg][2 * ks], sb2 = s[qg][2 * ks + 1];
                u32x4 pw;
                pw.x = pkh2(EXP2(sa[0]), EXP2(sa[1]));
                pw.y = pkh2(EXP2(sa[2]), EXP2(sa[3]));
                pw.z = pkh2(EXP2(sb2[0]), EXP2(sb2[1]));
                pw.w = pkh2(EXP2(sb2[2]), EXP2(sb2[3]));
                pb[qg][ks] = __builtin_bit_cast(f16x8, pw);
            }
    };

    // ---- pipeline: tile t stages t+1, computes QK(t), PV(t-1), exp(t) ----
    stageKV(0, 0, 0);
    __syncthreads();

    // t = 0 (no PV yet)
    stageKV(1, 1, 1);
    qk(0); expp(pbE);
    __syncthreads();

    // t = 1
    stageKV(0, 2, 2);
    qk(1); pv(0, pbE); expp(pbO);
    __syncthreads();

#pragma unroll 1
    for (int tb = 2; tb < 32; tb += 6) {
        // t = tb+0  (t%2=0, Vprev=(t-1)%3=1, stage t+1 -> K1,V0)
        stageKV(1, 0, tb + 1);
        qk(0); pv(1, pbO); expp(pbE);
        __syncthreads();
        // t = tb+1
        stageKV(0, 1, tb + 2);
        qk(1); pv(2, pbE); expp(pbO);
        __syncthreads();
        // t = tb+2
        stageKV(1, 2, tb + 3);
        qk(0); pv(0, pbO); expp(pbE);
        __syncthreads();
        // t = tb+3
        stageKV(0, 0, tb + 4);
        qk(1); pv(1, pbE); expp(pbO);
        __syncthreads();
        // t = tb+4
        stageKV(1, 1, tb + 5);
        qk(0); pv(2, pbO); expp(pbE);
        __syncthreads();
        // t = tb+5 (skip stage on the final tile t=31)
        if (tb + 6 < 32) stageKV(0, 2, tb + 6);
        qk(1); pv(0, pbE); expp(pbO);
        __syncthreads();
    }
    // epilogue: PV + l for t = 31 (V slot 31%3 = 1, odd tile -> pbO)
    pv(1, pbO);

    // ---- merge j-halves (exact: O and l add) via lane-to-lane LDS slots ----
    __syncthreads();                  // staging reads done; reuse as merge buf
    float* mrg = reinterpret_cast<float*>(smem);
    const int slot = (sub * 64 + lane) * 35;       // odd stride: no conflicts
    float lr[2] = { lacc[0][0], lacc[1][0] };
    if (jh == 1) {
#pragma unroll
        for (int qg = 0; qg < 2; ++qg) {
#pragma unroll
            for (int dt = 0; dt < 4; ++dt)
#pragma unroll
                for (int e = 0; e < 4; ++e)
                    mrg[slot + qg * 17 + dt * 4 + e] = oacc[qg][dt][e];
            mrg[slot + qg * 17 + 16] = lr[qg];
        }
    }
    __syncthreads();
    if (jh == 0) {
#pragma unroll
        for (int qg = 0; qg < 2; ++qg) {
            const float rl = RCP(lr[qg] + mrg[slot + qg * 17 + 16]);
            const size_t obase = ((size_t)bb * N_ + qbase + qg * 16 + l16) * C_ + h * D_;
#pragma unroll
            for (int dt = 0; dt < 4; ++dt) {
                float v0 = (oacc[qg][dt][0] + mrg[slot + qg * 17 + dt * 4 + 0]) * rl;
                float v1 = (oacc[qg][dt][1] + mrg[slot + qg * 17 + dt * 4 + 1]) * rl;
                float v2 = (oacc[qg][dt][2] + mrg[slot + qg * 17 + dt * 4 + 2]) * rl;
                float v3 = (oacc[qg][dt][3] + mrg[slot + qg * 17 + dt * 4 + 3]) * rl;
                u32x2 wv = { pk2(v0, v1), pk2(v2, v3) };
                *reinterpret_cast<u32x2*>(o + obase + dt * 16 + quad * 4) = wv;
            }
        }
    }
}

// ---------------------------------------------------------------------------
// Output projection — round-3 version.
// ---------------------------------------------------------------------------
__global__ __launch_bounds__(256, 2) void out_proj_fast(const bf16* __restrict__ ov,
                                                        const bf16* __restrict__ w,
                                                        const float* __restrict__ bias,
                                                        float* __restrict__ out)
{
    __shared__ short w_s[64][264];
    const int tid  = threadIdx.x;
    const int lane = tid & 63;
    const int wav  = tid >> 6;
    const int quad = lane >> 4;
    const int l16  = lane & 15;
    const int bid = (blockIdx.x & 7) * 64 + (blockIdx.x >> 3);   // 512 = 8*64
    const int m0 = (bid >> 2) * 128;
    const int n0 = (bid & 3) * 64;

    {
        const int row = tid >> 2, cb = (tid & 3) * 64;
        const bf16* src = w + (size_t)(n0 + row) * C_ + cb;
#pragma unroll
        for (int i = 0; i < 8; ++i)
            *reinterpret_cast<bf16x8*>(&w_s[row][cb + i * 8]) =
                *reinterpret_cast<const bf16x8*>(src + i * 8);
    }
    __syncthreads();

#pragma unroll
    for (int half = 0; half < 2; ++half) {
        const int mh = m0 + half * 64;
        f32x4 acc[4] = {{0,0,0,0},{0,0,0,0},{0,0,0,0},{0,0,0,0}};
        const bf16* orow = ov + (size_t)(mh + wav * 16 + l16) * C_ + quad * 8;
#pragma unroll
        for (int k0 = 0; k0 < C_; k0 += 32) {
            bf16x8 a = *reinterpret_cast<const bf16x8*>(orow + k0);
#pragma unroll
            for (int nt = 0; nt < 4; ++nt) {
                bf16x8 b = *reinterpret_cast<const bf16x8*>(&w_s[nt * 16 + l16][k0 + quad * 8]);
                acc[nt] = __builtin_amdgcn_mfma_f32_16x16x32_bf16(b, a, acc[nt], 0, 0, 0);
            }
        }
        const int m = mh + wav * 16 + l16;
#pragma unroll
        for (int nt = 0; nt < 4; ++nt) {
            const int oc0 = n0 + nt * 16 + quad * 4;
            f32x4 bv = *reinterpret_cast<const f32x4*>(bias + oc0);
            f32x4 ovv = acc[nt] + bv;
            *reinterpret_cast<f32x4*>(out + (size_t)m * C_ + oc0) = ovv;
        }
    }
}

extern "C" void kernel_launch(void* const* d_in, const int* in_sizes, int n_in,
                              void* d_out, int out_size, void* d_ws, size_t ws_size,
                              hipStream_t stream) {
    const float* x      = (const float*)d_in[0];
    const float* w_qkv  = (const float*)d_in[1];
    const float* w_proj = (const float*)d_in[2];
    const float* b_proj = (const float*)d_in[3];
    float* out = (float*)d_out;

    const size_t qkv_elems = (size_t)B_ * H_ * N_ * D_;   // 4,194,304
    bf16* q_ws  = (bf16*)d_ws;
    bf16* k_ws  = q_ws  + qkv_elems;
    f16*  vt_ws = (f16*)(k_ws + qkv_elems);
    bf16* o_ws  = (bf16*)(vt_ws + qkv_elems);
    bf16* x_bf  = o_ws  + qkv_elems;
    bf16* wq_bf = x_bf  + (size_t)B_ * N_ * C_;
    bf16* wp_bf = wq_bf + (size_t)3 * C_ * C_;

    cast_bf16    <<<2176, 256, 0, stream>>>(x, w_qkv, w_proj, x_bf, wq_bf, wp_bf);
    qkv_fast     <<<1536, 256, 0, stream>>>(x_bf, wq_bf, q_ws, k_ws, vt_ws);
    attn         <<< 512, 512, 0, stream>>>(q_ws, k_ws, vt_ws, o_ws);
    out_proj_fast<<< 512, 256, 0, stream>>>(o_ws, wp_bf, b_proj, out);
}

// Round 10
// 253.539 us; speedup vs baseline: 1.0335x; 1.0335x over previous
//
#include <hip/hip_runtime.h>
#include <hip/hip_bf16.h>

typedef __hip_bfloat16 bf16;
typedef _Float16 f16;
typedef __attribute__((ext_vector_type(8))) short bf16x8;
typedef __attribute__((ext_vector_type(8))) _Float16 f16x8;
typedef __attribute__((ext_vector_type(2))) _Float16 f16x2;
typedef __attribute__((ext_vector_type(4))) float f32x4;
typedef __attribute__((ext_vector_type(4))) unsigned int u32x4;
typedef __attribute__((ext_vector_type(2))) unsigned int u32x2;

#define B_ 4
#define N_ 4096
#define C_ 256
#define H_ 4
#define D_ 64
#define KLN 0.18033688011112042f   /* 0.125 * log2(e): folded into Q */

#if __has_builtin(__builtin_amdgcn_exp2f)
#define EXP2(x) __builtin_amdgcn_exp2f(x)
#else
#define EXP2(x) exp2f(x)
#endif
#if __has_builtin(__builtin_amdgcn_rcpf)
#define RCP(x) __builtin_amdgcn_rcpf(x)
#else
#define RCP(x) (1.0f / (x))
#endif

// direct global->LDS DMA, 16B per lane. LDS dest = wave-uniform base + lane*16.
__device__ inline void load_lds16(const void* g, void* l) {
#if __has_builtin(__builtin_amdgcn_global_load_lds)
    __builtin_amdgcn_global_load_lds(
        (const __attribute__((address_space(1))) unsigned int*)g,
        (__attribute__((address_space(3))) unsigned int*)l, 16, 0, 0);
#else
    int ln = __lane_id();
    ((u32x4*)l)[ln] = *((const u32x4*)g);   // fallback (not used on gfx950)
#endif
}

// two fp32 -> packed bf16 pair (round-half-up)
__device__ inline unsigned int pk2(float a, float b) {
    unsigned int ua = __builtin_bit_cast(unsigned int, a) + 0x8000u;
    unsigned int ub = __builtin_bit_cast(unsigned int, b) + 0x8000u;
    return (ua >> 16) | (ub & 0xffff0000u);
}
// two fp32 -> packed f16 pair (single v_cvt_pkrtz_f16_f32)
__device__ inline unsigned int pkh2(float a, float b) {
#if __has_builtin(__builtin_amdgcn_cvt_pkrtz)
    return __builtin_bit_cast(unsigned int, __builtin_amdgcn_cvt_pkrtz(a, b));
#else
    f16x2 h = { (f16)a, (f16)b };
    return __builtin_bit_cast(unsigned int, h);
#endif
}

// ---------------------------------------------------------------------------
// Prep: cast x, w_qkv, w_proj fp32 -> bf16 (memory-bound).
// ---------------------------------------------------------------------------
__global__ __launch_bounds__(256) void cast_bf16(const float* __restrict__ x,
                                                 const float* __restrict__ wq,
                                                 const float* __restrict__ wp,
                                                 bf16* __restrict__ xb,
                                                 bf16* __restrict__ wqb,
                                                 bf16* __restrict__ wpb)
{
    int bid = blockIdx.x;
    const float* s; bf16* d; int base;
    if (bid < 2048)      { s = x;  d = xb;  base = bid * 2048; }
    else if (bid < 2144) { s = wq; d = wqb; base = (bid - 2048) * 2048; }
    else                 { s = wp; d = wpb; base = (bid - 2144) * 2048; }
    int i = base + threadIdx.x * 8;
    f32x4 a = *reinterpret_cast<const f32x4*>(s + i);
    f32x4 b = *reinterpret_cast<const f32x4*>(s + i + 4);
    u32x4 o;
    o.x = pk2(a[0], a[1]); o.y = pk2(a[2], a[3]);
    o.z = pk2(b[0], b[1]); o.w = pk2(b[2], b[3]);
    *reinterpret_cast<u32x4*>(d + i) = o;
}

// ---------------------------------------------------------------------------
// QKV projection — round-3 version (best measured non-attn config).
// ---------------------------------------------------------------------------
__global__ __launch_bounds__(256, 2) void qkv_fast(const bf16* __restrict__ x,
                                                   const bf16* __restrict__ w,
                                                   bf16* __restrict__ qw,
                                                   bf16* __restrict__ kw,
                                                   f16* __restrict__ vtw)
{
    __shared__ short w_s[64][264];
    const int tid  = threadIdx.x;
    const int lane = tid & 63;
    const int wav  = tid >> 6;
    const int quad = lane >> 4;
    const int l16  = lane & 15;
    const int bid = (blockIdx.x & 7) * 192 + (blockIdx.x >> 3);   // 1536 = 8*192
    const int mt = bid / 12, nb = bid % 12;
    const int m0 = mt * 128, n0 = nb * 64;

    {
        const int row = tid >> 2, cb = (tid & 3) * 64;
        const bf16* src = w + (size_t)(n0 + row) * C_ + cb;
#pragma unroll
        for (int i = 0; i < 8; ++i)
            *reinterpret_cast<bf16x8*>(&w_s[row][cb + i * 8]) =
                *reinterpret_cast<const bf16x8*>(src + i * 8);
    }
    __syncthreads();

#pragma unroll
    for (int half = 0; half < 2; ++half) {
        const int mh = m0 + half * 64;
        f32x4 acc[4] = {{0,0,0,0},{0,0,0,0},{0,0,0,0},{0,0,0,0}};
        const bf16* xrow = x + (size_t)(mh + wav * 16 + l16) * C_ + quad * 8;
        if (nb < 8) {        // Q/K: transposed accumulator (swapped operands)
#pragma unroll
            for (int k0 = 0; k0 < C_; k0 += 32) {
                bf16x8 a = *reinterpret_cast<const bf16x8*>(xrow + k0);
#pragma unroll
                for (int nt = 0; nt < 4; ++nt) {
                    bf16x8 b = *reinterpret_cast<const bf16x8*>(&w_s[nt * 16 + l16][k0 + quad * 8]);
                    acc[nt] = __builtin_amdgcn_mfma_f32_16x16x32_bf16(b, a, acc[nt], 0, 0, 0);
                }
            }
        } else {             // V: normal orientation (store wants n-contiguous)
#pragma unroll
            for (int k0 = 0; k0 < C_; k0 += 32) {
                bf16x8 a = *reinterpret_cast<const bf16x8*>(xrow + k0);
#pragma unroll
                for (int nt = 0; nt < 4; ++nt) {
                    bf16x8 b = *reinterpret_cast<const bf16x8*>(&w_s[nt * 16 + l16][k0 + quad * 8]);
                    acc[nt] = __builtin_amdgcn_mfma_f32_16x16x32_bf16(a, b, acc[nt], 0, 0, 0);
                }
            }
        }

        const int bb = mh >> 12;
        const int nbase = (mh + wav * 16) & (N_ - 1);
        if (nb < 4) {                            // Q (scaled): row n = nbase+l16
            bf16* dst = qw + (((size_t)bb * H_ + nb) * N_ + nbase + l16) * D_;
#pragma unroll
            for (int nt = 0; nt < 4; ++nt) {
                u32x2 wv = { pk2(acc[nt][0] * KLN, acc[nt][1] * KLN),
                             pk2(acc[nt][2] * KLN, acc[nt][3] * KLN) };
                *reinterpret_cast<u32x2*>(dst + nt * 16 + quad * 4) = wv;
            }
        } else if (nb < 8) {                     // K
            bf16* dst = kw + (((size_t)bb * H_ + (nb - 4)) * N_ + nbase + l16) * D_;
#pragma unroll
            for (int nt = 0; nt < 4; ++nt) {
                u32x2 wv = { pk2(acc[nt][0], acc[nt][1]),
                             pk2(acc[nt][2], acc[nt][3]) };
                *reinterpret_cast<u32x2*>(dst + nt * 16 + quad * 4) = wv;
            }
        } else {                                 // V transposed, f16
            const int h = nb - 8;
#pragma unroll
            for (int nt = 0; nt < 4; ++nt) {
                int d = nt * 16 + l16;
                u32x2 wv;
                wv.x = pkh2(acc[nt][0], acc[nt][1]);
                wv.y = pkh2(acc[nt][2], acc[nt][3]);
                *reinterpret_cast<u32x2*>(
                    vtw + (((size_t)bb * H_ + h) * D_ + d) * N_ + nbase + quad * 4) = wv;
            }
        }
    }
}

// ---------------------------------------------------------------------------
// Flash attention v13 = v12's cross-tile PV pipeline with the scratch-spill
// bug removed. r9's counters (FETCH 216MB, WRITE 240MB vs 13/8 expected)
// showed the lambda pointer parameters (f16x8 (*pb)[2]) forced the P arrays
// into scratch — the pipeline was never actually tested. v13 uses token-
// pasting MACROS: every P/S access is a named array with compile-time
// indices, no address ever taken. K fragments load per-nt (8-reg transient,
// was 32) so the peak live set (~115 VGPR) fits the 128 budget at 4
// waves/SIMD. Schedule identical to v12: tile t stages t+1, computes QK(t),
// then PV(t-1) (prev-tile P from registers -> zero deps, queues ~36 MFMAs
// back-to-back), then exp(t) on the VALU under the MFMA drain. K 2-buf +
// V 3-buf = 80KB LDS, 2 blocks/CU. Accumulation order preserved ->
// bit-identical output.
// ---------------------------------------------------------------------------
__global__ __launch_bounds__(512, 4) void attn(const bf16* __restrict__ q,
                                               const bf16* __restrict__ k,
                                               const f16* __restrict__ vt,
                                               bf16* __restrict__ o)
{
    __shared__ __align__(16) char smem[81920];
    short* k_s = reinterpret_cast<short*>(smem);            // [2][jh][4096]
    f16*   v_s = reinterpret_cast<f16*>(smem + 32768);      // [3][jh][4096]

    const int tid  = threadIdx.x;
    const int lane = tid & 63;
    const int wav  = tid >> 6;       // 0..7
    const int quad = lane >> 4;
    const int l16  = lane & 15;
    const int l8   = lane & 7;
    const int sub  = wav & 3;        // 32-row q-slice within the 128-row tile
    const int jh   = wav >> 2;       // j-half

    const int wg = (blockIdx.x & 7) * 64 + (blockIdx.x >> 3);  // XCD swizzle
    const int bh = wg >> 5;
    const int qt = wg & 31;
    const int bb = bh >> 2, h = bh & 3;

    const bf16* qp = q  + (size_t)bh * N_ * D_;
    const bf16* kp = k  + (size_t)bh * N_ * D_;
    const f16*  vp = vt + (size_t)bh * D_ * N_;

    const int qbase = qt * 128 + sub * 32;
    bf16x8 qb[2][2];
#pragma unroll
    for (int qg = 0; qg < 2; ++qg)
#pragma unroll
        for (int ks = 0; ks < 2; ++ks)
            qb[qg][ks] = *reinterpret_cast<const bf16x8*>(
                qp + (size_t)(qbase + qg * 16 + l16) * D_ + ks * 32 + quad * 8);

    // staging geometry: lane -> (row ri, stored slot ci); logical chunk = ci^ri
    const int ri = lane >> 3;
    const int ci = lane & 7;
    const int gc = ci ^ ri;
    int koff[2], voff[2], lds_r[2];
#pragma unroll
    for (int g = 0; g < 2; ++g) {
        const int rb  = sub * 16 + g * 8;
        const int rho = rb + ri;
        const int pr  = (rho & 32) | ((rho & 12) << 1) | ((rho & 16) >> 2) | (rho & 3);
        koff[g]  = pr * D_ + gc * 8;          // K: permuted row, swizzled chunk
        voff[g]  = rho * N_ + gc * 8;         // V: linear d-row, swizzled chunk
        lds_r[g] = rb * 64;
    }

    f32x4 oacc[2][4];
    f32x4 lacc[2];
#pragma unroll
    for (int qg = 0; qg < 2; ++qg) {
        lacc[qg] = (f32x4){0, 0, 0, 0};
#pragma unroll
        for (int dt = 0; dt < 4; ++dt) oacc[qg][dt] = (f32x4){0, 0, 0, 0};
    }
    const f16x8 onesA = {1.f16, 1.f16, 1.f16, 1.f16, 1.f16, 1.f16, 1.f16, 1.f16};

    f32x4 s[2][4];                  // this tile's S^T (QK output, pre-exp)
    f16x8 pbE[2][2], pbO[2][2];     // P fragments: even / odd tiles

// stage tile t into K buf kbuf, V slot vslot
#define STAGE(kbuf, vslot, t) do {                                            \
    const int j0_ = jh * 2048 + (t) * 64;                                     \
    short* kd_ = k_s + ((kbuf) * 2 + jh) * 4096;                              \
    f16*   vd_ = v_s + ((vslot) * 2 + jh) * 4096;                             \
    load_lds16(kp + (size_t)j0_ * D_ + koff[0], kd_ + lds_r[0]);              \
    load_lds16(kp + (size_t)j0_ * D_ + koff[1], kd_ + lds_r[1]);              \
    load_lds16(vp + j0_ + voff[0],              vd_ + lds_r[0]);              \
    load_lds16(vp + j0_ + voff[1],              vd_ + lds_r[1]);              \
} while (0)

// QK(t): S^T = K.Q^T from K buffer kbuf (per-nt K fragments: 8-reg transient)
#define QK(kbuf) do {                                                         \
    const short* kt_ = k_s + ((kbuf) * 2 + jh) * 4096;                        \
    _Pragma("unroll")                                                         \
    for (int nt = 0; nt < 4; ++nt) {                                          \
        const int rb_ = (nt * 16 + l16) * 64;                                 \
        bf16x8 ka0_ = *reinterpret_cast<const bf16x8*>(kt_ + rb_ + ((quad    ) ^ l8) * 8); \
        bf16x8 ka1_ = *reinterpret_cast<const bf16x8*>(kt_ + rb_ + ((4 + quad) ^ l8) * 8); \
        _Pragma("unroll")                                                     \
        for (int qg = 0; qg < 2; ++qg) {                                      \
            s[qg][nt] = __builtin_amdgcn_mfma_f32_16x16x32_bf16(              \
                ka0_, qb[qg][0], (f32x4){0.f, 0.f, 0.f, 0.f}, 0, 0, 0);       \
            s[qg][nt] = __builtin_amdgcn_mfma_f32_16x16x32_bf16(              \
                ka1_, qb[qg][1], s[qg][nt], 0, 0, 0);                         \
        }                                                                     \
    }                                                                         \
} while (0)

// PV(t-1) + l(t-1): consumes PB (named array, compile-time indices)
#define PV(vslot, PB) do {                                                    \
    const f16* vt_ = v_s + ((vslot) * 2 + jh) * 4096;                         \
    lacc[0] = __builtin_amdgcn_mfma_f32_16x16x32_f16(onesA, PB[0][0], lacc[0], 0, 0, 0); \
    lacc[0] = __builtin_amdgcn_mfma_f32_16x16x32_f16(onesA, PB[0][1], lacc[0], 0, 0, 0); \
    lacc[1] = __builtin_amdgcn_mfma_f32_16x16x32_f16(onesA, PB[1][0], lacc[1], 0, 0, 0); \
    lacc[1] = __builtin_amdgcn_mfma_f32_16x16x32_f16(onesA, PB[1][1], lacc[1], 0, 0, 0); \
    _Pragma("unroll")                                                         \
    for (int ks = 0; ks < 2; ++ks) {                                          \
        _Pragma("unroll")                                                     \
        for (int dt = 0; dt < 4; ++dt) {                                      \
            f16x8 va_ = *reinterpret_cast<const f16x8*>(                      \
                vt_ + (dt * 16 + l16) * 64 + (((ks << 2) + quad) ^ l8) * 8);  \
            oacc[0][dt] = __builtin_amdgcn_mfma_f32_16x16x32_f16(va_, PB[0][ks], oacc[0][dt], 0, 0, 0); \
            oacc[1][dt] = __builtin_amdgcn_mfma_f32_16x16x32_f16(va_, PB[1][ks], oacc[1][dt], 0, 0, 0); \
        }                                                                     \
    }                                                                         \
} while (0)

// exp(t): p = exp2(s) -> PB (VALU; overlaps the PV MFMA drain)
#define EXPP(PB) do {                                                         \
    _Pragma("unroll")                                                         \
    for (int qg = 0; qg < 2; ++qg) {                                          \
        _Pragma("unroll")                                                     \
        for (int ks = 0; ks < 2; ++ks) {                                      \
            const f32x4 sa_ = s[qg][2 * ks], sb_ = s[qg][2 * ks + 1];         \
            u32x4 pw_;                                                        \
            pw_.x = pkh2(EXP2(sa_[0]), EXP2(sa_[1]));                         \
            pw_.y = pkh2(EXP2(sa_[2]), EXP2(sa_[3]));                         \
            pw_.z = pkh2(EXP2(sb_[0]), EXP2(sb_[1]));                         \
            pw_.w = pkh2(EXP2(sb_[2]), EXP2(sb_[3]));                         \
            PB[qg][ks] = __builtin_bit_cast(f16x8, pw_);                      \
        }                                                                     \
    }                                                                         \
} while (0)

    // ---- pipeline: tile t stages t+1, computes QK(t), PV(t-1), exp(t) ----
    STAGE(0, 0, 0);
    __syncthreads();

    // t = 0 (no PV yet)
    STAGE(1, 1, 1);
    QK(0); EXPP(pbE);
    __syncthreads();

    // t = 1
    STAGE(0, 2, 2);
    QK(1); PV(0, pbE); EXPP(pbO);
    __syncthreads();

#pragma unroll 1
    for (int tb = 2; tb < 32; tb += 6) {
        // t = tb+0
        STAGE(1, 0, tb + 1);
        QK(0); PV(1, pbO); EXPP(pbE);
        __syncthreads();
        // t = tb+1
        STAGE(0, 1, tb + 2);
        QK(1); PV(2, pbE); EXPP(pbO);
        __syncthreads();
        // t = tb+2
        STAGE(1, 2, tb + 3);
        QK(0); PV(0, pbO); EXPP(pbE);
        __syncthreads();
        // t = tb+3
        STAGE(0, 0, tb + 4);
        QK(1); PV(1, pbE); EXPP(pbO);
        __syncthreads();
        // t = tb+4
        STAGE(1, 1, tb + 5);
        QK(0); PV(2, pbO); EXPP(pbE);
        __syncthreads();
        // t = tb+5 (skip stage on the final tile t=31)
        if (tb + 6 < 32) STAGE(0, 2, tb + 6);
        QK(1); PV(0, pbE); EXPP(pbO);
        __syncthreads();
    }
    // epilogue: PV + l for t = 31 (V slot 31%3 = 1, odd tile -> pbO)
    PV(1, pbO);

    // ---- merge j-halves (exact: O and l add) via lane-to-lane LDS slots ----
    __syncthreads();                  // staging reads done; reuse as merge buf
    float* mrg = reinterpret_cast<float*>(smem);
    const int slot = (sub * 64 + lane) * 35;       // odd stride: no conflicts
    if (jh == 1) {
#pragma unroll
        for (int qg = 0; qg < 2; ++qg) {
#pragma unroll
            for (int dt = 0; dt < 4; ++dt)
#pragma unroll
                for (int e = 0; e < 4; ++e)
                    mrg[slot + qg * 17 + dt * 4 + e] = oacc[qg][dt][e];
            mrg[slot + qg * 17 + 16] = lacc[qg][0];
        }
    }
    __syncthreads();
    if (jh == 0) {
#pragma unroll
        for (int qg = 0; qg < 2; ++qg) {
            const float rl = RCP(lacc[qg][0] + mrg[slot + qg * 17 + 16]);
            const size_t obase = ((size_t)bb * N_ + qbase + qg * 16 + l16) * C_ + h * D_;
#pragma unroll
            for (int dt = 0; dt < 4; ++dt) {
                float v0 = (oacc[qg][dt][0] + mrg[slot + qg * 17 + dt * 4 + 0]) * rl;
                float v1 = (oacc[qg][dt][1] + mrg[slot + qg * 17 + dt * 4 + 1]) * rl;
                float v2 = (oacc[qg][dt][2] + mrg[slot + qg * 17 + dt * 4 + 2]) * rl;
                float v3 = (oacc[qg][dt][3] + mrg[slot + qg * 17 + dt * 4 + 3]) * rl;
                u32x2 wv = { pk2(v0, v1), pk2(v2, v3) };
                *reinterpret_cast<u32x2*>(o + obase + dt * 16 + quad * 4) = wv;
            }
        }
    }
}

// ---------------------------------------------------------------------------
// Output projection — round-3 version.
// ---------------------------------------------------------------------------
__global__ __launch_bounds__(256, 2) void out_proj_fast(const bf16* __restrict__ ov,
                                                        const bf16* __restrict__ w,
                                                        const float* __restrict__ bias,
                                                        float* __restrict__ out)
{
    __shared__ short w_s[64][264];
    const int tid  = threadIdx.x;
    const int lane = tid & 63;
    const int wav  = tid >> 6;
    const int quad = lane >> 4;
    const int l16  = lane & 15;
    const int bid = (blockIdx.x & 7) * 64 + (blockIdx.x >> 3);   // 512 = 8*64
    const int m0 = (bid >> 2) * 128;
    const int n0 = (bid & 3) * 64;

    {
        const int row = tid >> 2, cb = (tid & 3) * 64;
        const bf16* src = w + (size_t)(n0 + row) * C_ + cb;
#pragma unroll
        for (int i = 0; i < 8; ++i)
            *reinterpret_cast<bf16x8*>(&w_s[row][cb + i * 8]) =
                *reinterpret_cast<const bf16x8*>(src + i * 8);
    }
    __syncthreads();

#pragma unroll
    for (int half = 0; half < 2; ++half) {
        const int mh = m0 + half * 64;
        f32x4 acc[4] = {{0,0,0,0},{0,0,0,0},{0,0,0,0},{0,0,0,0}};
        const bf16* orow = ov + (size_t)(mh + wav * 16 + l16) * C_ + quad * 8;
#pragma unroll
        for (int k0 = 0; k0 < C_; k0 += 32) {
            bf16x8 a = *reinterpret_cast<const bf16x8*>(orow + k0);
#pragma unroll
            for (int nt = 0; nt < 4; ++nt) {
                bf16x8 b = *reinterpret_cast<const bf16x8*>(&w_s[nt * 16 + l16][k0 + quad * 8]);
                acc[nt] = __builtin_amdgcn_mfma_f32_16x16x32_bf16(b, a, acc[nt], 0, 0, 0);
            }
        }
        const int m = mh + wav * 16 + l16;
#pragma unroll
        for (int nt = 0; nt < 4; ++nt) {
            const int oc0 = n0 + nt * 16 + quad * 4;
            f32x4 bv = *reinterpret_cast<const f32x4*>(bias + oc0);
            f32x4 ovv = acc[nt] + bv;
            *reinterpret_cast<f32x4*>(out + (size_t)m * C_ + oc0) = ovv;
        }
    }
}

extern "C" void kernel_launch(void* const* d_in, const int* in_sizes, int n_in,
                              void* d_out, int out_size, void* d_ws, size_t ws_size,
                              hipStream_t stream) {
    const float* x      = (const float*)d_in[0];
    const float* w_qkv  = (const float*)d_in[1];
    const float* w_proj = (const float*)d_in[2];
    const float* b_proj = (const float*)d_in[3];
    float* out = (float*)d_out;

    const size_t qkv_elems = (size_t)B_ * H_ * N_ * D_;   // 4,194,304
    bf16* q_ws  = (bf16*)d_ws;
    bf16* k_ws  = q_ws  + qkv_elems;
    f16*  vt_ws = (f16*)(k_ws + qkv_elems);
    bf16* o_ws  = (bf16*)(vt_ws + qkv_elems);
    bf16* x_bf  = o_ws  + qkv_elems;
    bf16* wq_bf = x_bf  + (size_t)B_ * N_ * C_;
    bf16* wp_bf = wq_bf + (size_t)3 * C_ * C_;

    cast_bf16    <<<2176, 256, 0, stream>>>(x, w_qkv, w_proj, x_bf, wq_bf, wp_bf);
    qkv_fast     <<<1536, 256, 0, stream>>>(x_bf, wq_bf, q_ws, k_ws, vt_ws);
    attn         <<< 512, 512, 0, stream>>>(q_ws, k_ws, vt_ws, o_ws);
    out_proj_fast<<< 512, 256, 0, stream>>>(o_ws, wp_bf, b_proj, out);
}

// Round 11
// 186.115 us; speedup vs baseline: 1.4079x; 1.3623x over previous
//
#include <hip/hip_runtime.h>
#include <hip/hip_bf16.h>

typedef __hip_bfloat16 bf16;
typedef _Float16 f16;
typedef __attribute__((ext_vector_type(8))) short bf16x8;
typedef __attribute__((ext_vector_type(8))) _Float16 f16x8;
typedef __attribute__((ext_vector_type(2))) _Float16 f16x2;
typedef __attribute__((ext_vector_type(4))) float f32x4;
typedef __attribute__((ext_vector_type(4))) unsigned int u32x4;
typedef __attribute__((ext_vector_type(2))) unsigned int u32x2;

#define B_ 4
#define N_ 4096
#define C_ 256
#define H_ 4
#define D_ 64
#define KLN 0.18033688011112042f   /* 0.125 * log2(e): folded into Q */

#if __has_builtin(__builtin_amdgcn_exp2f)
#define EXP2(x) __builtin_amdgcn_exp2f(x)
#else
#define EXP2(x) exp2f(x)
#endif
#if __has_builtin(__builtin_amdgcn_rcpf)
#define RCP(x) __builtin_amdgcn_rcpf(x)
#else
#define RCP(x) (1.0f / (x))
#endif

// direct global->LDS DMA, 16B per lane. LDS dest = wave-uniform base + lane*16.
__device__ inline void load_lds16(const void* g, void* l) {
#if __has_builtin(__builtin_amdgcn_global_load_lds)
    __builtin_amdgcn_global_load_lds(
        (const __attribute__((address_space(1))) unsigned int*)g,
        (__attribute__((address_space(3))) unsigned int*)l, 16, 0, 0);
#else
    int ln = __lane_id();
    ((u32x4*)l)[ln] = *((const u32x4*)g);   // fallback (not used on gfx950)
#endif
}

// two fp32 -> packed bf16 pair (round-half-up)
__device__ inline unsigned int pk2(float a, float b) {
    unsigned int ua = __builtin_bit_cast(unsigned int, a) + 0x8000u;
    unsigned int ub = __builtin_bit_cast(unsigned int, b) + 0x8000u;
    return (ua >> 16) | (ub & 0xffff0000u);
}
// two fp32 -> packed f16 pair (single v_cvt_pkrtz_f16_f32)
__device__ inline unsigned int pkh2(float a, float b) {
#if __has_builtin(__builtin_amdgcn_cvt_pkrtz)
    return __builtin_bit_cast(unsigned int, __builtin_amdgcn_cvt_pkrtz(a, b));
#else
    f16x2 h = { (f16)a, (f16)b };
    return __builtin_bit_cast(unsigned int, h);
#endif
}

// ---------------------------------------------------------------------------
// Prep: cast x, w_qkv, w_proj fp32 -> bf16 (memory-bound).
// ---------------------------------------------------------------------------
__global__ __launch_bounds__(256) void cast_bf16(const float* __restrict__ x,
                                                 const float* __restrict__ wq,
                                                 const float* __restrict__ wp,
                                                 bf16* __restrict__ xb,
                                                 bf16* __restrict__ wqb,
                                                 bf16* __restrict__ wpb)
{
    int bid = blockIdx.x;
    const float* s; bf16* d; int base;
    if (bid < 2048)      { s = x;  d = xb;  base = bid * 2048; }
    else if (bid < 2144) { s = wq; d = wqb; base = (bid - 2048) * 2048; }
    else                 { s = wp; d = wpb; base = (bid - 2144) * 2048; }
    int i = base + threadIdx.x * 8;
    f32x4 a = *reinterpret_cast<const f32x4*>(s + i);
    f32x4 b = *reinterpret_cast<const f32x4*>(s + i + 4);
    u32x4 o;
    o.x = pk2(a[0], a[1]); o.y = pk2(a[2], a[3]);
    o.z = pk2(b[0], b[1]); o.w = pk2(b[2], b[3]);
    *reinterpret_cast<u32x4*>(d + i) = o;
}

// ---------------------------------------------------------------------------
// QKV projection — round-3 version (best measured non-attn config).
// ---------------------------------------------------------------------------
__global__ __launch_bounds__(256, 2) void qkv_fast(const bf16* __restrict__ x,
                                                   const bf16* __restrict__ w,
                                                   bf16* __restrict__ qw,
                                                   bf16* __restrict__ kw,
                                                   f16* __restrict__ vtw)
{
    __shared__ short w_s[64][264];
    const int tid  = threadIdx.x;
    const int lane = tid & 63;
    const int wav  = tid >> 6;
    const int quad = lane >> 4;
    const int l16  = lane & 15;
    const int bid = (blockIdx.x & 7) * 192 + (blockIdx.x >> 3);   // 1536 = 8*192
    const int mt = bid / 12, nb = bid % 12;
    const int m0 = mt * 128, n0 = nb * 64;

    {
        const int row = tid >> 2, cb = (tid & 3) * 64;
        const bf16* src = w + (size_t)(n0 + row) * C_ + cb;
#pragma unroll
        for (int i = 0; i < 8; ++i)
            *reinterpret_cast<bf16x8*>(&w_s[row][cb + i * 8]) =
                *reinterpret_cast<const bf16x8*>(src + i * 8);
    }
    __syncthreads();

#pragma unroll
    for (int half = 0; half < 2; ++half) {
        const int mh = m0 + half * 64;
        f32x4 acc[4] = {{0,0,0,0},{0,0,0,0},{0,0,0,0},{0,0,0,0}};
        const bf16* xrow = x + (size_t)(mh + wav * 16 + l16) * C_ + quad * 8;
        if (nb < 8) {        // Q/K: transposed accumulator (swapped operands)
#pragma unroll
            for (int k0 = 0; k0 < C_; k0 += 32) {
                bf16x8 a = *reinterpret_cast<const bf16x8*>(xrow + k0);
#pragma unroll
                for (int nt = 0; nt < 4; ++nt) {
                    bf16x8 b = *reinterpret_cast<const bf16x8*>(&w_s[nt * 16 + l16][k0 + quad * 8]);
                    acc[nt] = __builtin_amdgcn_mfma_f32_16x16x32_bf16(b, a, acc[nt], 0, 0, 0);
                }
            }
        } else {             // V: normal orientation (store wants n-contiguous)
#pragma unroll
            for (int k0 = 0; k0 < C_; k0 += 32) {
                bf16x8 a = *reinterpret_cast<const bf16x8*>(xrow + k0);
#pragma unroll
                for (int nt = 0; nt < 4; ++nt) {
                    bf16x8 b = *reinterpret_cast<const bf16x8*>(&w_s[nt * 16 + l16][k0 + quad * 8]);
                    acc[nt] = __builtin_amdgcn_mfma_f32_16x16x32_bf16(a, b, acc[nt], 0, 0, 0);
                }
            }
        }

        const int bb = mh >> 12;
        const int nbase = (mh + wav * 16) & (N_ - 1);
        if (nb < 4) {                            // Q (scaled): row n = nbase+l16
            bf16* dst = qw + (((size_t)bb * H_ + nb) * N_ + nbase + l16) * D_;
#pragma unroll
            for (int nt = 0; nt < 4; ++nt) {
                u32x2 wv = { pk2(acc[nt][0] * KLN, acc[nt][1] * KLN),
                             pk2(acc[nt][2] * KLN, acc[nt][3] * KLN) };
                *reinterpret_cast<u32x2*>(dst + nt * 16 + quad * 4) = wv;
            }
        } else if (nb < 8) {                     // K
            bf16* dst = kw + (((size_t)bb * H_ + (nb - 4)) * N_ + nbase + l16) * D_;
#pragma unroll
            for (int nt = 0; nt < 4; ++nt) {
                u32x2 wv = { pk2(acc[nt][0], acc[nt][1]),
                             pk2(acc[nt][2], acc[nt][3]) };
                *reinterpret_cast<u32x2*>(dst + nt * 16 + quad * 4) = wv;
            }
        } else {                                 // V transposed, f16
            const int h = nb - 8;
#pragma unroll
            for (int nt = 0; nt < 4; ++nt) {
                int d = nt * 16 + l16;
                u32x2 wv;
                wv.x = pkh2(acc[nt][0], acc[nt][1]);
                wv.y = pkh2(acc[nt][2], acc[nt][3]);
                *reinterpret_cast<u32x2*>(
                    vtw + (((size_t)bb * H_ + h) * D_ + d) * N_ + nbase + quad * 4) = wv;
            }
        }
    }
}

// ---------------------------------------------------------------------------
// Flash attention v14 = v13's cross-tile PV pipeline + the allocator fix.
// r8/r9/r10 all show VGPR_Count=64 for 512-thread blocks: the allocator
// TARGETS 64 VGPR (8 waves/EU) regardless of launch_bounds' minimum, and the
// pipeline's ~120-reg live set then spills ~60 regs -> 500MB scratch traffic
// (r10: FETCH 220MB / WRITE 309MB). amdgpu_waves_per_eu(4,4) clamps BOTH
// bounds -> allocator budgets the full 128 VGPR for exactly our residency
// (2 blocks/CU x 8 waves). Pressure refinement: PV(t-1) runs FIRST in the
// tile body (zero deps at tile start; P_prev dies before s is born), pinned
// by sched_barrier(0); QK's ds_reads hide under PV's 20-MFMA drain; exp(t)
// runs on the VALU under the combined 36-MFMA backlog. K 2-buf + V 3-buf =
// 80KB LDS. Accumulation order across tiles unchanged -> bit-identical.
// ---------------------------------------------------------------------------
__global__ __launch_bounds__(512)
__attribute__((amdgpu_waves_per_eu(4, 4)))
void attn(const bf16* __restrict__ q,
          const bf16* __restrict__ k,
          const f16* __restrict__ vt,
          bf16* __restrict__ o)
{
    __shared__ __align__(16) char smem[81920];
    short* k_s = reinterpret_cast<short*>(smem);            // [2][jh][4096]
    f16*   v_s = reinterpret_cast<f16*>(smem + 32768);      // [3][jh][4096]

    const int tid  = threadIdx.x;
    const int lane = tid & 63;
    const int wav  = tid >> 6;       // 0..7
    const int quad = lane >> 4;
    const int l16  = lane & 15;
    const int l8   = lane & 7;
    const int sub  = wav & 3;        // 32-row q-slice within the 128-row tile
    const int jh   = wav >> 2;       // j-half

    const int wg = (blockIdx.x & 7) * 64 + (blockIdx.x >> 3);  // XCD swizzle
    const int bh = wg >> 5;
    const int qt = wg & 31;
    const int bb = bh >> 2, h = bh & 3;

    const bf16* qp = q  + (size_t)bh * N_ * D_;
    const bf16* kp = k  + (size_t)bh * N_ * D_;
    const f16*  vp = vt + (size_t)bh * D_ * N_;

    const int qbase = qt * 128 + sub * 32;
    bf16x8 qb[2][2];
#pragma unroll
    for (int qg = 0; qg < 2; ++qg)
#pragma unroll
        for (int ks = 0; ks < 2; ++ks)
            qb[qg][ks] = *reinterpret_cast<const bf16x8*>(
                qp + (size_t)(qbase + qg * 16 + l16) * D_ + ks * 32 + quad * 8);

    // staging geometry: lane -> (row ri, stored slot ci); logical chunk = ci^ri
    const int ri = lane >> 3;
    const int ci = lane & 7;
    const int gc = ci ^ ri;
    int koff[2], voff[2], lds_r[2];
#pragma unroll
    for (int g = 0; g < 2; ++g) {
        const int rb  = sub * 16 + g * 8;
        const int rho = rb + ri;
        const int pr  = (rho & 32) | ((rho & 12) << 1) | ((rho & 16) >> 2) | (rho & 3);
        koff[g]  = pr * D_ + gc * 8;          // K: permuted row, swizzled chunk
        voff[g]  = rho * N_ + gc * 8;         // V: linear d-row, swizzled chunk
        lds_r[g] = rb * 64;
    }

    f32x4 oacc[2][4];
    f32x4 lacc[2];
#pragma unroll
    for (int qg = 0; qg < 2; ++qg) {
        lacc[qg] = (f32x4){0, 0, 0, 0};
#pragma unroll
        for (int dt = 0; dt < 4; ++dt) oacc[qg][dt] = (f32x4){0, 0, 0, 0};
    }
    const f16x8 onesA = {1.f16, 1.f16, 1.f16, 1.f16, 1.f16, 1.f16, 1.f16, 1.f16};

    f32x4 s[2][4];                  // this tile's S^T (QK output, pre-exp)
    f16x8 pbE[2][2], pbO[2][2];     // P fragments: even / odd tiles

// stage tile t into K buf kbuf, V slot vslot
#define STAGE(kbuf, vslot, t) do {                                            \
    const int j0_ = jh * 2048 + (t) * 64;                                     \
    short* kd_ = k_s + ((kbuf) * 2 + jh) * 4096;                              \
    f16*   vd_ = v_s + ((vslot) * 2 + jh) * 4096;                             \
    load_lds16(kp + (size_t)j0_ * D_ + koff[0], kd_ + lds_r[0]);              \
    load_lds16(kp + (size_t)j0_ * D_ + koff[1], kd_ + lds_r[1]);              \
    load_lds16(vp + j0_ + voff[0],              vd_ + lds_r[0]);              \
    load_lds16(vp + j0_ + voff[1],              vd_ + lds_r[1]);              \
} while (0)

// QK(t): S^T = K.Q^T from K buffer kbuf (per-nt K fragments: 8-reg transient)
#define QK(kbuf) do {                                                         \
    const short* kt_ = k_s + ((kbuf) * 2 + jh) * 4096;                        \
    _Pragma("unroll")                                                         \
    for (int nt = 0; nt < 4; ++nt) {                                          \
        const int rb_ = (nt * 16 + l16) * 64;                                 \
        bf16x8 ka0_ = *reinterpret_cast<const bf16x8*>(kt_ + rb_ + ((quad    ) ^ l8) * 8); \
        bf16x8 ka1_ = *reinterpret_cast<const bf16x8*>(kt_ + rb_ + ((4 + quad) ^ l8) * 8); \
        _Pragma("unroll")                                                     \
        for (int qg = 0; qg < 2; ++qg) {                                      \
            s[qg][nt] = __builtin_amdgcn_mfma_f32_16x16x32_bf16(              \
                ka0_, qb[qg][0], (f32x4){0.f, 0.f, 0.f, 0.f}, 0, 0, 0);       \
            s[qg][nt] = __builtin_amdgcn_mfma_f32_16x16x32_bf16(              \
                ka1_, qb[qg][1], s[qg][nt], 0, 0, 0);                         \
        }                                                                     \
    }                                                                         \
} while (0)

// PV(t-1) + l(t-1): consumes PB (named array, compile-time indices)
#define PV(vslot, PB) do {                                                    \
    const f16* vt_ = v_s + ((vslot) * 2 + jh) * 4096;                         \
    lacc[0] = __builtin_amdgcn_mfma_f32_16x16x32_f16(onesA, PB[0][0], lacc[0], 0, 0, 0); \
    lacc[0] = __builtin_amdgcn_mfma_f32_16x16x32_f16(onesA, PB[0][1], lacc[0], 0, 0, 0); \
    lacc[1] = __builtin_amdgcn_mfma_f32_16x16x32_f16(onesA, PB[1][0], lacc[1], 0, 0, 0); \
    lacc[1] = __builtin_amdgcn_mfma_f32_16x16x32_f16(onesA, PB[1][1], lacc[1], 0, 0, 0); \
    _Pragma("unroll")                                                         \
    for (int ks = 0; ks < 2; ++ks) {                                          \
        _Pragma("unroll")                                                     \
        for (int dt = 0; dt < 4; ++dt) {                                      \
            f16x8 va_ = *reinterpret_cast<const f16x8*>(                      \
                vt_ + (dt * 16 + l16) * 64 + (((ks << 2) + quad) ^ l8) * 8);  \
            oacc[0][dt] = __builtin_amdgcn_mfma_f32_16x16x32_f16(va_, PB[0][ks], oacc[0][dt], 0, 0, 0); \
            oacc[1][dt] = __builtin_amdgcn_mfma_f32_16x16x32_f16(va_, PB[1][ks], oacc[1][dt], 0, 0, 0); \
        }                                                                     \
    }                                                                         \
} while (0)

// exp(t): p = exp2(s) -> PB (VALU; overlaps the PV+QK MFMA drain)
#define EXPP(PB) do {                                                         \
    _Pragma("unroll")                                                         \
    for (int qg = 0; qg < 2; ++qg) {                                          \
        _Pragma("unroll")                                                     \
        for (int ks = 0; ks < 2; ++ks) {                                      \
            const f32x4 sa_ = s[qg][2 * ks], sb_ = s[qg][2 * ks + 1];         \
            u32x4 pw_;                                                        \
            pw_.x = pkh2(EXP2(sa_[0]), EXP2(sa_[1]));                         \
            pw_.y = pkh2(EXP2(sa_[2]), EXP2(sa_[3]));                         \
            pw_.z = pkh2(EXP2(sb_[0]), EXP2(sb_[1]));                         \
            pw_.w = pkh2(EXP2(sb_[2]), EXP2(sb_[3]));                         \
            PB[qg][ks] = __builtin_bit_cast(f16x8, pw_);                      \
        }                                                                     \
    }                                                                         \
} while (0)

#define SB __builtin_amdgcn_sched_barrier(0)

    // ---- pipeline: tile t = {stage t+1 | PV(t-1) | QK(t) | exp(t)} ----
    STAGE(0, 0, 0);
    __syncthreads();

    // t = 0 (no PV yet)
    STAGE(1, 1, 1);
    QK(0); EXPP(pbE);
    __syncthreads();

    // t = 1
    STAGE(0, 2, 2);
    PV(0, pbE); SB; QK(1); EXPP(pbO);
    __syncthreads();

#pragma unroll 1
    for (int tb = 2; tb < 32; tb += 6) {
        // t = tb+0
        STAGE(1, 0, tb + 1);
        PV(1, pbO); SB; QK(0); EXPP(pbE);
        __syncthreads();
        // t = tb+1
        STAGE(0, 1, tb + 2);
        PV(2, pbE); SB; QK(1); EXPP(pbO);
        __syncthreads();
        // t = tb+2
        STAGE(1, 2, tb + 3);
        PV(0, pbO); SB; QK(0); EXPP(pbE);
        __syncthreads();
        // t = tb+3
        STAGE(0, 0, tb + 4);
        PV(1, pbE); SB; QK(1); EXPP(pbO);
        __syncthreads();
        // t = tb+4
        STAGE(1, 1, tb + 5);
        PV(2, pbO); SB; QK(0); EXPP(pbE);
        __syncthreads();
        // t = tb+5 (skip stage on the final tile t=31)
        if (tb + 6 < 32) STAGE(0, 2, tb + 6);
        PV(0, pbE); SB; QK(1); EXPP(pbO);
        __syncthreads();
    }
    // epilogue: PV + l for t = 31 (V(31) in slot 31%3=1, odd tile -> pbO)
    PV(1, pbO);

    // ---- merge j-halves (exact: O and l add) via lane-to-lane LDS slots ----
    __syncthreads();                  // staging reads done; reuse as merge buf
    float* mrg = reinterpret_cast<float*>(smem);
    const int slot = (sub * 64 + lane) * 35;       // odd stride: no conflicts
    if (jh == 1) {
#pragma unroll
        for (int qg = 0; qg < 2; ++qg) {
#pragma unroll
            for (int dt = 0; dt < 4; ++dt)
#pragma unroll
                for (int e = 0; e < 4; ++e)
                    mrg[slot + qg * 17 + dt * 4 + e] = oacc[qg][dt][e];
            mrg[slot + qg * 17 + 16] = lacc[qg][0];
        }
    }
    __syncthreads();
    if (jh == 0) {
#pragma unroll
        for (int qg = 0; qg < 2; ++qg) {
            const float rl = RCP(lacc[qg][0] + mrg[slot + qg * 17 + 16]);
            const size_t obase = ((size_t)bb * N_ + qbase + qg * 16 + l16) * C_ + h * D_;
#pragma unroll
            for (int dt = 0; dt < 4; ++dt) {
                float v0 = (oacc[qg][dt][0] + mrg[slot + qg * 17 + dt * 4 + 0]) * rl;
                float v1 = (oacc[qg][dt][1] + mrg[slot + qg * 17 + dt * 4 + 1]) * rl;
                float v2 = (oacc[qg][dt][2] + mrg[slot + qg * 17 + dt * 4 + 2]) * rl;
                float v3 = (oacc[qg][dt][3] + mrg[slot + qg * 17 + dt * 4 + 3]) * rl;
                u32x2 wv = { pk2(v0, v1), pk2(v2, v3) };
                *reinterpret_cast<u32x2*>(o + obase + dt * 16 + quad * 4) = wv;
            }
        }
    }
}

// ---------------------------------------------------------------------------
// Output projection — round-3 version.
// ---------------------------------------------------------------------------
__global__ __launch_bounds__(256, 2) void out_proj_fast(const bf16* __restrict__ ov,
                                                        const bf16* __restrict__ w,
                                                        const float* __restrict__ bias,
                                                        float* __restrict__ out)
{
    __shared__ short w_s[64][264];
    const int tid  = threadIdx.x;
    const int lane = tid & 63;
    const int wav  = tid >> 6;
    const int quad = lane >> 4;
    const int l16  = lane & 15;
    const int bid = (blockIdx.x & 7) * 64 + (blockIdx.x >> 3);   // 512 = 8*64
    const int m0 = (bid >> 2) * 128;
    const int n0 = (bid & 3) * 64;

    {
        const int row = tid >> 2, cb = (tid & 3) * 64;
        const bf16* src = w + (size_t)(n0 + row) * C_ + cb;
#pragma unroll
        for (int i = 0; i < 8; ++i)
            *reinterpret_cast<bf16x8*>(&w_s[row][cb + i * 8]) =
                *reinterpret_cast<const bf16x8*>(src + i * 8);
    }
    __syncthreads();

#pragma unroll
    for (int half = 0; half < 2; ++half) {
        const int mh = m0 + half * 64;
        f32x4 acc[4] = {{0,0,0,0},{0,0,0,0},{0,0,0,0},{0,0,0,0}};
        const bf16* orow = ov + (size_t)(mh + wav * 16 + l16) * C_ + quad * 8;
#pragma unroll
        for (int k0 = 0; k0 < C_; k0 += 32) {
            bf16x8 a = *reinterpret_cast<const bf16x8*>(orow + k0);
#pragma unroll
            for (int nt = 0; nt < 4; ++nt) {
                bf16x8 b = *reinterpret_cast<const bf16x8*>(&w_s[nt * 16 + l16][k0 + quad * 8]);
                acc[nt] = __builtin_amdgcn_mfma_f32_16x16x32_bf16(b, a, acc[nt], 0, 0, 0);
            }
        }
        const int m = mh + wav * 16 + l16;
#pragma unroll
        for (int nt = 0; nt < 4; ++nt) {
            const int oc0 = n0 + nt * 16 + quad * 4;
            f32x4 bv = *reinterpret_cast<const f32x4*>(bias + oc0);
            f32x4 ovv = acc[nt] + bv;
            *reinterpret_cast<f32x4*>(out + (size_t)m * C_ + oc0) = ovv;
        }
    }
}

extern "C" void kernel_launch(void* const* d_in, const int* in_sizes, int n_in,
                              void* d_out, int out_size, void* d_ws, size_t ws_size,
                              hipStream_t stream) {
    const float* x      = (const float*)d_in[0];
    const float* w_qkv  = (const float*)d_in[1];
    const float* w_proj = (const float*)d_in[2];
    const float* b_proj = (const float*)d_in[3];
    float* out = (float*)d_out;

    const size_t qkv_elems = (size_t)B_ * H_ * N_ * D_;   // 4,194,304
    bf16* q_ws  = (bf16*)d_ws;
    bf16* k_ws  = q_ws  + qkv_elems;
    f16*  vt_ws = (f16*)(k_ws + qkv_elems);
    bf16* o_ws  = (bf16*)(vt_ws + qkv_elems);
    bf16* x_bf  = o_ws  + qkv_elems;
    bf16* wq_bf = x_bf  + (size_t)B_ * N_ * C_;
    bf16* wp_bf = wq_bf + (size_t)3 * C_ * C_;

    cast_bf16    <<<2176, 256, 0, stream>>>(x, w_qkv, w_proj, x_bf, wq_bf, wp_bf);
    qkv_fast     <<<1536, 256, 0, stream>>>(x_bf, wq_bf, q_ws, k_ws, vt_ws);
    attn         <<< 512, 512, 0, stream>>>(q_ws, k_ws, vt_ws, o_ws);
    out_proj_fast<<< 512, 256, 0, stream>>>(o_ws, wp_bf, b_proj, out);
}

// Round 12
// 174.250 us; speedup vs baseline: 1.5037x; 1.0681x over previous
//
#include <hip/hip_runtime.h>
#include <hip/hip_bf16.h>

typedef __hip_bfloat16 bf16;
typedef _Float16 f16;
typedef __attribute__((ext_vector_type(8))) short bf16x8;
typedef __attribute__((ext_vector_type(8))) _Float16 f16x8;
typedef __attribute__((ext_vector_type(2))) _Float16 f16x2;
typedef __attribute__((ext_vector_type(4))) float f32x4;
typedef __attribute__((ext_vector_type(4))) unsigned int u32x4;
typedef __attribute__((ext_vector_type(2))) unsigned int u32x2;

#define B_ 4
#define N_ 4096
#define C_ 256
#define H_ 4
#define D_ 64
#define KLN 0.18033688011112042f   /* 0.125 * log2(e): folded into Q */

#if __has_builtin(__builtin_amdgcn_exp2f)
#define EXP2(x) __builtin_amdgcn_exp2f(x)
#else
#define EXP2(x) exp2f(x)
#endif
#if __has_builtin(__builtin_amdgcn_rcpf)
#define RCP(x) __builtin_amdgcn_rcpf(x)
#else
#define RCP(x) (1.0f / (x))
#endif

// direct global->LDS DMA, 16B per lane. LDS dest = wave-uniform base + lane*16.
__device__ inline void load_lds16(const void* g, void* l) {
#if __has_builtin(__builtin_amdgcn_global_load_lds)
    __builtin_amdgcn_global_load_lds(
        (const __attribute__((address_space(1))) unsigned int*)g,
        (__attribute__((address_space(3))) unsigned int*)l, 16, 0, 0);
#else
    int ln = __lane_id();
    ((u32x4*)l)[ln] = *((const u32x4*)g);   // fallback (not used on gfx950)
#endif
}

// two fp32 -> packed bf16 pair (round-half-up)
__device__ inline unsigned int pk2(float a, float b) {
    unsigned int ua = __builtin_bit_cast(unsigned int, a) + 0x8000u;
    unsigned int ub = __builtin_bit_cast(unsigned int, b) + 0x8000u;
    return (ua >> 16) | (ub & 0xffff0000u);
}
// two fp32 -> packed f16 pair (single v_cvt_pkrtz_f16_f32)
__device__ inline unsigned int pkh2(float a, float b) {
#if __has_builtin(__builtin_amdgcn_cvt_pkrtz)
    return __builtin_bit_cast(unsigned int, __builtin_amdgcn_cvt_pkrtz(a, b));
#else
    f16x2 h = { (f16)a, (f16)b };
    return __builtin_bit_cast(unsigned int, h);
#endif
}

// ---------------------------------------------------------------------------
// Prep: cast x, w_qkv, w_proj fp32 -> bf16 (memory-bound).
// ---------------------------------------------------------------------------
__global__ __launch_bounds__(256) void cast_bf16(const float* __restrict__ x,
                                                 const float* __restrict__ wq,
                                                 const float* __restrict__ wp,
                                                 bf16* __restrict__ xb,
                                                 bf16* __restrict__ wqb,
                                                 bf16* __restrict__ wpb)
{
    int bid = blockIdx.x;
    const float* s; bf16* d; int base;
    if (bid < 2048)      { s = x;  d = xb;  base = bid * 2048; }
    else if (bid < 2144) { s = wq; d = wqb; base = (bid - 2048) * 2048; }
    else                 { s = wp; d = wpb; base = (bid - 2144) * 2048; }
    int i = base + threadIdx.x * 8;
    f32x4 a = *reinterpret_cast<const f32x4*>(s + i);
    f32x4 b = *reinterpret_cast<const f32x4*>(s + i + 4);
    u32x4 o;
    o.x = pk2(a[0], a[1]); o.y = pk2(a[2], a[3]);
    o.z = pk2(b[0], b[1]); o.w = pk2(b[2], b[3]);
    *reinterpret_cast<u32x4*>(d + i) = o;
}

// ---------------------------------------------------------------------------
// QKV projection — round-3 version (best measured non-attn config).
// ---------------------------------------------------------------------------
__global__ __launch_bounds__(256, 2) void qkv_fast(const bf16* __restrict__ x,
                                                   const bf16* __restrict__ w,
                                                   bf16* __restrict__ qw,
                                                   bf16* __restrict__ kw,
                                                   f16* __restrict__ vtw)
{
    __shared__ short w_s[64][264];
    const int tid  = threadIdx.x;
    const int lane = tid & 63;
    const int wav  = tid >> 6;
    const int quad = lane >> 4;
    const int l16  = lane & 15;
    const int bid = (blockIdx.x & 7) * 192 + (blockIdx.x >> 3);   // 1536 = 8*192
    const int mt = bid / 12, nb = bid % 12;
    const int m0 = mt * 128, n0 = nb * 64;

    {
        const int row = tid >> 2, cb = (tid & 3) * 64;
        const bf16* src = w + (size_t)(n0 + row) * C_ + cb;
#pragma unroll
        for (int i = 0; i < 8; ++i)
            *reinterpret_cast<bf16x8*>(&w_s[row][cb + i * 8]) =
                *reinterpret_cast<const bf16x8*>(src + i * 8);
    }
    __syncthreads();

#pragma unroll
    for (int half = 0; half < 2; ++half) {
        const int mh = m0 + half * 64;
        f32x4 acc[4] = {{0,0,0,0},{0,0,0,0},{0,0,0,0},{0,0,0,0}};
        const bf16* xrow = x + (size_t)(mh + wav * 16 + l16) * C_ + quad * 8;
        if (nb < 8) {        // Q/K: transposed accumulator (swapped operands)
#pragma unroll
            for (int k0 = 0; k0 < C_; k0 += 32) {
                bf16x8 a = *reinterpret_cast<const bf16x8*>(xrow + k0);
#pragma unroll
                for (int nt = 0; nt < 4; ++nt) {
                    bf16x8 b = *reinterpret_cast<const bf16x8*>(&w_s[nt * 16 + l16][k0 + quad * 8]);
                    acc[nt] = __builtin_amdgcn_mfma_f32_16x16x32_bf16(b, a, acc[nt], 0, 0, 0);
                }
            }
        } else {             // V: normal orientation (store wants n-contiguous)
#pragma unroll
            for (int k0 = 0; k0 < C_; k0 += 32) {
                bf16x8 a = *reinterpret_cast<const bf16x8*>(xrow + k0);
#pragma unroll
                for (int nt = 0; nt < 4; ++nt) {
                    bf16x8 b = *reinterpret_cast<const bf16x8*>(&w_s[nt * 16 + l16][k0 + quad * 8]);
                    acc[nt] = __builtin_amdgcn_mfma_f32_16x16x32_bf16(a, b, acc[nt], 0, 0, 0);
                }
            }
        }

        const int bb = mh >> 12;
        const int nbase = (mh + wav * 16) & (N_ - 1);
        if (nb < 4) {                            // Q (scaled): row n = nbase+l16
            bf16* dst = qw + (((size_t)bb * H_ + nb) * N_ + nbase + l16) * D_;
#pragma unroll
            for (int nt = 0; nt < 4; ++nt) {
                u32x2 wv = { pk2(acc[nt][0] * KLN, acc[nt][1] * KLN),
                             pk2(acc[nt][2] * KLN, acc[nt][3] * KLN) };
                *reinterpret_cast<u32x2*>(dst + nt * 16 + quad * 4) = wv;
            }
        } else if (nb < 8) {                     // K
            bf16* dst = kw + (((size_t)bb * H_ + (nb - 4)) * N_ + nbase + l16) * D_;
#pragma unroll
            for (int nt = 0; nt < 4; ++nt) {
                u32x2 wv = { pk2(acc[nt][0], acc[nt][1]),
                             pk2(acc[nt][2], acc[nt][3]) };
                *reinterpret_cast<u32x2*>(dst + nt * 16 + quad * 4) = wv;
            }
        } else {                                 // V transposed, f16
            const int h = nb - 8;
#pragma unroll
            for (int nt = 0; nt < 4; ++nt) {
                int d = nt * 16 + l16;
                u32x2 wv;
                wv.x = pkh2(acc[nt][0], acc[nt][1]);
                wv.y = pkh2(acc[nt][2], acc[nt][3]);
                *reinterpret_cast<u32x2*>(
                    vtw + (((size_t)bb * H_ + h) * D_ + d) * N_ + nbase + quad * 4) = wv;
            }
        }
    }
}

// ---------------------------------------------------------------------------
// Flash attention v15 = v14's cross-tile PV pipeline re-hosted in 256-thread
// blocks. r8-r11 proved the compiler pins 512-thread workgroups at 64 VGPR
// (every attribute failed to move it) -> the ~120-reg pipeline always spilled.
// 256-thread builds measured 120-128 VGPR with no spill (r3/r4/r6), so:
// 4 waves x 32 q-rows = same 128-row q-tile, NO j-half split — each block
// walks all 64 j-tiles (merge phase deleted). K 2-buf + V 3-buf = 40KB LDS,
// 2 blocks/CU, 8 waves/CU. Per tile: PV(t-1) first (prev-tile P in regs,
// zero deps -> 36 MFMAs queue back-to-back), QK(t), exp(t) on the VALU under
// the MFMA drain (early-fragment exp overlaps late QK MFMAs). pbE/pbO never
// overlap (prev set dies in PV before the new set is born) -> peak live
// ~110 VGPR. 6-periodic schedule (K parity x V mod-3), tail t=62,63,
// epilogue PV. oacc summed sequentially over j (was 2 halves + add):
// same values, order shift <= 1 ulp.
// ---------------------------------------------------------------------------
__global__ __launch_bounds__(256, 2) void attn(const bf16* __restrict__ q,
                                               const bf16* __restrict__ k,
                                               const f16* __restrict__ vt,
                                               bf16* __restrict__ o)
{
    __shared__ __align__(16) char smem[40960];
    short* k_s = reinterpret_cast<short*>(smem);            // [2][4096] bf16
    f16*   v_s = reinterpret_cast<f16*>(smem + 16384);      // [3][4096] f16

    const int tid  = threadIdx.x;
    const int lane = tid & 63;
    const int wav  = tid >> 6;       // 0..3: q-sub (32 rows each)
    const int quad = lane >> 4;
    const int l16  = lane & 15;
    const int l8   = lane & 7;

    const int wg = (blockIdx.x & 7) * 64 + (blockIdx.x >> 3);  // XCD swizzle
    const int bh = wg >> 5;
    const int qt = wg & 31;
    const int bb = bh >> 2, h = bh & 3;

    const bf16* qp = q  + (size_t)bh * N_ * D_;
    const bf16* kp = k  + (size_t)bh * N_ * D_;
    const f16*  vp = vt + (size_t)bh * D_ * N_;

    const int qbase = qt * 128 + wav * 32;
    bf16x8 qb[2][2];
#pragma unroll
    for (int qg = 0; qg < 2; ++qg)
#pragma unroll
        for (int ks = 0; ks < 2; ++ks)
            qb[qg][ks] = *reinterpret_cast<const bf16x8*>(
                qp + (size_t)(qbase + qg * 16 + l16) * D_ + ks * 32 + quad * 8);

    // staging geometry: lane -> (row ri, stored slot ci); logical chunk = ci^ri
    const int ri = lane >> 3;
    const int ci = lane & 7;
    const int gc = ci ^ ri;
    int koff[2], voff[2], lds_r[2];
#pragma unroll
    for (int g = 0; g < 2; ++g) {
        const int rb  = wav * 16 + g * 8;     // this wave stages 16 rows of 64
        const int rho = rb + ri;
        const int pr  = (rho & 32) | ((rho & 12) << 1) | ((rho & 16) >> 2) | (rho & 3);
        koff[g]  = pr * D_ + gc * 8;          // K: permuted row, swizzled chunk
        voff[g]  = rho * N_ + gc * 8;         // V: linear d-row, swizzled chunk
        lds_r[g] = rb * 64;
    }

    f32x4 oacc[2][4];
    f32x4 lacc[2];
#pragma unroll
    for (int qg = 0; qg < 2; ++qg) {
        lacc[qg] = (f32x4){0, 0, 0, 0};
#pragma unroll
        for (int dt = 0; dt < 4; ++dt) oacc[qg][dt] = (f32x4){0, 0, 0, 0};
    }
    const f16x8 onesA = {1.f16, 1.f16, 1.f16, 1.f16, 1.f16, 1.f16, 1.f16, 1.f16};

    f32x4 s[2][4];                  // this tile's S^T (QK output, pre-exp)
    f16x8 pbE[2][2], pbO[2][2];     // P fragments: even / odd tiles

// stage tile t into K buf kbuf, V slot vslot
#define STAGE(kbuf, vslot, t) do {                                            \
    const int j0_ = (t) * 64;                                                 \
    short* kd_ = k_s + (kbuf) * 4096;                                         \
    f16*   vd_ = v_s + (vslot) * 4096;                                        \
    load_lds16(kp + (size_t)j0_ * D_ + koff[0], kd_ + lds_r[0]);              \
    load_lds16(kp + (size_t)j0_ * D_ + koff[1], kd_ + lds_r[1]);              \
    load_lds16(vp + j0_ + voff[0],              vd_ + lds_r[0]);              \
    load_lds16(vp + j0_ + voff[1],              vd_ + lds_r[1]);              \
} while (0)

// QK(t): S^T = K.Q^T from K buffer kbuf (per-nt K fragments: 8-reg transient)
#define QK(kbuf) do {                                                         \
    const short* kt_ = k_s + (kbuf) * 4096;                                   \
    _Pragma("unroll")                                                         \
    for (int nt = 0; nt < 4; ++nt) {                                          \
        const int rb_ = (nt * 16 + l16) * 64;                                 \
        bf16x8 ka0_ = *reinterpret_cast<const bf16x8*>(kt_ + rb_ + ((quad    ) ^ l8) * 8); \
        bf16x8 ka1_ = *reinterpret_cast<const bf16x8*>(kt_ + rb_ + ((4 + quad) ^ l8) * 8); \
        _Pragma("unroll")                                                     \
        for (int qg = 0; qg < 2; ++qg) {                                      \
            s[qg][nt] = __builtin_amdgcn_mfma_f32_16x16x32_bf16(              \
                ka0_, qb[qg][0], (f32x4){0.f, 0.f, 0.f, 0.f}, 0, 0, 0);       \
            s[qg][nt] = __builtin_amdgcn_mfma_f32_16x16x32_bf16(              \
                ka1_, qb[qg][1], s[qg][nt], 0, 0, 0);                         \
        }                                                                     \
    }                                                                         \
} while (0)

// PV(t-1) + l(t-1): consumes PB (named array, compile-time indices)
#define PV(vslot, PB) do {                                                    \
    const f16* vt_ = v_s + (vslot) * 4096;                                    \
    lacc[0] = __builtin_amdgcn_mfma_f32_16x16x32_f16(onesA, PB[0][0], lacc[0], 0, 0, 0); \
    lacc[0] = __builtin_amdgcn_mfma_f32_16x16x32_f16(onesA, PB[0][1], lacc[0], 0, 0, 0); \
    lacc[1] = __builtin_amdgcn_mfma_f32_16x16x32_f16(onesA, PB[1][0], lacc[1], 0, 0, 0); \
    lacc[1] = __builtin_amdgcn_mfma_f32_16x16x32_f16(onesA, PB[1][1], lacc[1], 0, 0, 0); \
    _Pragma("unroll")                                                         \
    for (int ks = 0; ks < 2; ++ks) {                                          \
        _Pragma("unroll")                                                     \
        for (int dt = 0; dt < 4; ++dt) {                                      \
            f16x8 va_ = *reinterpret_cast<const f16x8*>(                      \
                vt_ + (dt * 16 + l16) * 64 + (((ks << 2) + quad) ^ l8) * 8);  \
            oacc[0][dt] = __builtin_amdgcn_mfma_f32_16x16x32_f16(va_, PB[0][ks], oacc[0][dt], 0, 0, 0); \
            oacc[1][dt] = __builtin_amdgcn_mfma_f32_16x16x32_f16(va_, PB[1][ks], oacc[1][dt], 0, 0, 0); \
        }                                                                     \
    }                                                                         \
} while (0)

// exp(t): p = exp2(s) -> PB (VALU; overlaps the PV+QK MFMA drain)
#define EXPP(PB) do {                                                         \
    _Pragma("unroll")                                                         \
    for (int qg = 0; qg < 2; ++qg) {                                          \
        _Pragma("unroll")                                                     \
        for (int ks = 0; ks < 2; ++ks) {                                      \
            const f32x4 sa_ = s[qg][2 * ks], sb_ = s[qg][2 * ks + 1];         \
            u32x4 pw_;                                                        \
            pw_.x = pkh2(EXP2(sa_[0]), EXP2(sa_[1]));                         \
            pw_.y = pkh2(EXP2(sa_[2]), EXP2(sa_[3]));                         \
            pw_.z = pkh2(EXP2(sb_[0]), EXP2(sb_[1]));                         \
            pw_.w = pkh2(EXP2(sb_[2]), EXP2(sb_[3]));                         \
            PB[qg][ks] = __builtin_bit_cast(f16x8, pw_);                      \
        }                                                                     \
    }                                                                         \
} while (0)

#define SB __builtin_amdgcn_sched_barrier(0)

    // ---- pipeline: tile t = {stage t+1 | PV(t-1) | QK(t) | exp(t)} ----
    STAGE(0, 0, 0);
    __syncthreads();

    // t = 0 (no PV yet)
    STAGE(1, 1, 1);
    QK(0); EXPP(pbE);
    __syncthreads();

    // t = 1
    STAGE(0, 2, 2);
    PV(0, pbE); SB; QK(1); EXPP(pbO);
    __syncthreads();

#pragma unroll 1
    for (int tb = 2; tb <= 56; tb += 6) {
        // t = tb+0  (t%6==2)
        STAGE(1, 0, tb + 1);
        PV(1, pbO); SB; QK(0); EXPP(pbE);
        __syncthreads();
        // t = tb+1  (t%6==3)
        STAGE(0, 1, tb + 2);
        PV(2, pbE); SB; QK(1); EXPP(pbO);
        __syncthreads();
        // t = tb+2  (t%6==4)
        STAGE(1, 2, tb + 3);
        PV(0, pbO); SB; QK(0); EXPP(pbE);
        __syncthreads();
        // t = tb+3  (t%6==5)
        STAGE(0, 0, tb + 4);
        PV(1, pbE); SB; QK(1); EXPP(pbO);
        __syncthreads();
        // t = tb+4  (t%6==0)
        STAGE(1, 1, tb + 5);
        PV(2, pbO); SB; QK(0); EXPP(pbE);
        __syncthreads();
        // t = tb+5  (t%6==1)
        STAGE(0, 2, tb + 6);
        PV(0, pbE); SB; QK(1); EXPP(pbO);
        __syncthreads();
    }
    // tail: t = 62 (t%6==2)
    STAGE(1, 0, 63);
    PV(1, pbO); SB; QK(0); EXPP(pbE);
    __syncthreads();
    // tail: t = 63 (t%6==3), no stage
    PV(2, pbE); SB; QK(1); EXPP(pbO);
    // epilogue: PV + l for t = 63 (V(63) in slot 0, odd tile -> pbO)
    PV(0, pbO);

    // ---- normalize + store (no j-half merge needed) ----
#pragma unroll
    for (int qg = 0; qg < 2; ++qg) {
        const float rl = RCP(lacc[qg][0]);
        const size_t obase = ((size_t)bb * N_ + qbase + qg * 16 + l16) * C_ + h * D_;
#pragma unroll
        for (int dt = 0; dt < 4; ++dt) {
            float v0 = oacc[qg][dt][0] * rl;
            float v1 = oacc[qg][dt][1] * rl;
            float v2 = oacc[qg][dt][2] * rl;
            float v3 = oacc[qg][dt][3] * rl;
            u32x2 wv = { pk2(v0, v1), pk2(v2, v3) };
            *reinterpret_cast<u32x2*>(o + obase + dt * 16 + quad * 4) = wv;
        }
    }
}

// ---------------------------------------------------------------------------
// Output projection — round-3 version.
// ---------------------------------------------------------------------------
__global__ __launch_bounds__(256, 2) void out_proj_fast(const bf16* __restrict__ ov,
                                                        const bf16* __restrict__ w,
                                                        const float* __restrict__ bias,
                                                        float* __restrict__ out)
{
    __shared__ short w_s[64][264];
    const int tid  = threadIdx.x;
    const int lane = tid & 63;
    const int wav  = tid >> 6;
    const int quad = lane >> 4;
    const int l16  = lane & 15;
    const int bid = (blockIdx.x & 7) * 64 + (blockIdx.x >> 3);   // 512 = 8*64
    const int m0 = (bid >> 2) * 128;
    const int n0 = (bid & 3) * 64;

    {
        const int row = tid >> 2, cb = (tid & 3) * 64;
        const bf16* src = w + (size_t)(n0 + row) * C_ + cb;
#pragma unroll
        for (int i = 0; i < 8; ++i)
            *reinterpret_cast<bf16x8*>(&w_s[row][cb + i * 8]) =
                *reinterpret_cast<const bf16x8*>(src + i * 8);
    }
    __syncthreads();

#pragma unroll
    for (int half = 0; half < 2; ++half) {
        const int mh = m0 + half * 64;
        f32x4 acc[4] = {{0,0,0,0},{0,0,0,0},{0,0,0,0},{0,0,0,0}};
        const bf16* orow = ov + (size_t)(mh + wav * 16 + l16) * C_ + quad * 8;
#pragma unroll
        for (int k0 = 0; k0 < C_; k0 += 32) {
            bf16x8 a = *reinterpret_cast<const bf16x8*>(orow + k0);
#pragma unroll
            for (int nt = 0; nt < 4; ++nt) {
                bf16x8 b = *reinterpret_cast<const bf16x8*>(&w_s[nt * 16 + l16][k0 + quad * 8]);
                acc[nt] = __builtin_amdgcn_mfma_f32_16x16x32_bf16(b, a, acc[nt], 0, 0, 0);
            }
        }
        const int m = mh + wav * 16 + l16;
#pragma unroll
        for (int nt = 0; nt < 4; ++nt) {
            const int oc0 = n0 + nt * 16 + quad * 4;
            f32x4 bv = *reinterpret_cast<const f32x4*>(bias + oc0);
            f32x4 ovv = acc[nt] + bv;
            *reinterpret_cast<f32x4*>(out + (size_t)m * C_ + oc0) = ovv;
        }
    }
}

extern "C" void kernel_launch(void* const* d_in, const int* in_sizes, int n_in,
                              void* d_out, int out_size, void* d_ws, size_t ws_size,
                              hipStream_t stream) {
    const float* x      = (const float*)d_in[0];
    const float* w_qkv  = (const float*)d_in[1];
    const float* w_proj = (const float*)d_in[2];
    const float* b_proj = (const float*)d_in[3];
    float* out = (float*)d_out;

    const size_t qkv_elems = (size_t)B_ * H_ * N_ * D_;   // 4,194,304
    bf16* q_ws  = (bf16*)d_ws;
    bf16* k_ws  = q_ws  + qkv_elems;
    f16*  vt_ws = (f16*)(k_ws + qkv_elems);
    bf16* o_ws  = (bf16*)(vt_ws + qkv_elems);
    bf16* x_bf  = o_ws  + qkv_elems;
    bf16* wq_bf = x_bf  + (size_t)B_ * N_ * C_;
    bf16* wp_bf = wq_bf + (size_t)3 * C_ * C_;

    cast_bf16    <<<2176, 256, 0, stream>>>(x, w_qkv, w_proj, x_bf, wq_bf, wp_bf);
    qkv_fast     <<<1536, 256, 0, stream>>>(x_bf, wq_bf, q_ws, k_ws, vt_ws);
    attn         <<< 512, 256, 0, stream>>>(q_ws, k_ws, vt_ws, o_ws);
    out_proj_fast<<< 512, 256, 0, stream>>>(o_ws, wp_bf, b_proj, out);
}